// Round 5
// baseline (107.938 us; speedup 1.0000x reference)
//
#include <hip/hip_runtime.h>
#include <hip/hip_bf16.h>

#define B_ 2
#define S_ 2048
#define D_ 1024
#define N_ 16
#define H_ 64

typedef unsigned short u16;
typedef unsigned int u32;
typedef __bf16 bf16x8 __attribute__((ext_vector_type(8)));
typedef u16 u16x8 __attribute__((ext_vector_type(8)));
typedef u32 u32x2 __attribute__((ext_vector_type(2)));
typedef float f4v __attribute__((ext_vector_type(4)));

__device__ __forceinline__ u16 f2b(float f) {
    u32 u = __builtin_bit_cast(u32, f);
    u32 r = (u + 0x7FFFu + ((u >> 16) & 1u)) >> 16;
    return (u16)r;
}
__device__ __forceinline__ bf16x8 asbf(u16x8 v) { return __builtin_bit_cast(bf16x8, v); }
__device__ __forceinline__ u32 cvtpk(float a, float b) {
    u32 r;
    asm("v_cvt_pk_bf16_f32 %0, %1, %2" : "=v"(r) : "v"(a), "v"(b));
    return r;
}

// ---------------------------------------------------------------------------
// convert x fp32 -> bf16 [4096][1024]
__global__ __launch_bounds__(256) void k_cvt_x(const float* __restrict__ x,
                                               u16* __restrict__ xb) {
    size_t i = ((size_t)blockIdx.x * 256 + threadIdx.x) * 8;
    float4 f0 = *(const float4*)(x + i);
    float4 f1 = *(const float4*)(x + i + 4);
    u16x8 o;
    o[0] = f2b(f0.x); o[1] = f2b(f0.y); o[2] = f2b(f0.z); o[3] = f2b(f0.w);
    o[4] = f2b(f1.x); o[5] = f2b(f1.y); o[6] = f2b(f1.z); o[7] = f2b(f1.w);
    *(u16x8*)(xb + i) = o;
}

// ---------------------------------------------------------------------------
// W_qkv fp32 [n][1024 d][192 j] -> bf16 TRANSPOSED wt [n][192 j][1024 d].
// Q columns (j<64) scaled by 0.125*log2(e) (exp2-domain softmax).
__global__ __launch_bounds__(256) void k_cvt_w(const float* __restrict__ w,
                                               u16* __restrict__ wt) {
    __shared__ float T[64][65];
    const int d0 = blockIdx.x * 64, jt = blockIdx.y, n = blockIdx.z;
    const int j0 = jt * 64;
    const float sc = (jt == 0) ? 0.125f * 1.44269504089f : 1.0f;
    const int t = threadIdx.x;
#pragma unroll
    for (int rep = 0; rep < 4; ++rep) {
        int v = t + rep * 256;
        int row = v >> 4, c4 = v & 15;
        float4 f = *(const float4*)(w + ((size_t)(n * 1024 + d0 + row)) * 192 + j0 + c4 * 4);
        T[row][c4 * 4 + 0] = f.x * sc;
        T[row][c4 * 4 + 1] = f.y * sc;
        T[row][c4 * 4 + 2] = f.z * sc;
        T[row][c4 * 4 + 3] = f.w * sc;
    }
    __syncthreads();
#pragma unroll
    for (int rep = 0; rep < 2; ++rep) {
        int c = t + rep * 256;
        int j = c >> 3, db = c & 7;
        u16x8 o;
#pragma unroll
        for (int e = 0; e < 8; ++e) o[e] = f2b(T[db * 8 + e][j]);
        *(u16x8*)(wt + ((size_t)(n * 192 + j0 + j)) * 1024 + d0 + db * 8) = o;
    }
}

// ---------------------------------------------------------------------------
// wsum[d] = sum over 1024 rows of W_out
__global__ __launch_bounds__(256) void k_wsum(const float* __restrict__ Wout,
                                              float* __restrict__ wsum) {
    __shared__ float red[16][17];
    const int dd = threadIdx.x & 15, rr = threadIdx.x >> 4;
    const int d = blockIdx.x * 16 + dd;
    float s = 0.f;
    for (int r = rr * 64; r < rr * 64 + 64; ++r) s += Wout[(size_t)r * 1024 + d];
    red[rr][dd] = s;
    __syncthreads();
    if (rr == 0) {
        float t = 0.f;
#pragma unroll
        for (int k = 0; k < 16; ++k) t += red[k][dd];
        wsum[d] = t;
    }
}

// ---------------------------------------------------------------------------
// QKV GEMM, MFMA bf16. Tile 128(M) x 192(N) x 64(K-step). 8 waves as 2M x 4N;
// wave tile 64x48 (4 m-subtiles x 3 fj) -> 14 b128 reads per 24 MFMA.
__global__ __launch_bounds__(512) void k_qkv(const u16* __restrict__ xb,
                                             const u16* __restrict__ wt,
                                             u16* __restrict__ qbuf,
                                             u16* __restrict__ kbuf,
                                             u16* __restrict__ vt) {
    __shared__ u16 As[128 * 64];   // [row][64k] swizzled
    __shared__ u16 Bst[192 * 64];  // [j][64k]  swizzled
    const int st = blockIdx.x, n = blockIdx.y;
    const int t = threadIdx.x;
    const int w = t >> 6, lane = t & 63, hi2 = lane >> 4, lo4 = lane & 15;
    const int wm = w >> 2, wn = w & 3;  // 2M x 4N wave grid

    // A staging: 512 thr, 2 chunks (32B) each: row t>>2, k-slice (t&3)*16
    const int arow = t >> 2, aq4 = t & 3;
    const u16* Ag = xb + (size_t)(st * 128 + arow) * 1024 + aq4 * 16;
    const int asw = (arow & 7) << 3;
    u16* Al0 = As + arow * 64 + ((aq4 * 16 + 0) ^ asw);
    u16* Al1 = As + arow * 64 + ((aq4 * 16 + 8) ^ asw);
    // B staging: 3 chunks: v = rep*512 + t, j = v>>3, off = (v&7)*8
    const int bj = t >> 3, boff = (t & 7) * 8;
    const u16* Bg0 = wt + (size_t)(n * 192 + bj) * 1024 + boff;        // j 0..63
    const u16* Bg1 = Bg0 + (size_t)64 * 1024;                          // j 64..127
    const u16* Bg2 = Bg0 + (size_t)128 * 1024;                         // j 128..191
    const int bsw = boff ^ ((bj & 7) << 3);
    u16* Bl0 = Bst + (bj + 0) * 64 + bsw;
    u16* Bl1 = Bst + (bj + 64) * 64 + bsw;
    u16* Bl2 = Bst + (bj + 128) * 64 + bsw;

    f4v acc[4][3];
#pragma unroll
    for (int i = 0; i < 4; ++i)
#pragma unroll
        for (int j = 0; j < 3; ++j) acc[i][j] = (f4v){0.f, 0.f, 0.f, 0.f};

    const int rsw = (lo4 & 7) << 3;
    u16x8 ra0 = *(const u16x8*)(Ag);
    u16x8 ra1 = *(const u16x8*)(Ag + 8);
    u16x8 rb0 = *(const u16x8*)(Bg0);
    u16x8 rb1 = *(const u16x8*)(Bg1);
    u16x8 rb2 = *(const u16x8*)(Bg2);

    for (int kk = 0; kk < 16; ++kk) {
        __syncthreads();
        *(u16x8*)Al0 = ra0;
        *(u16x8*)Al1 = ra1;
        *(u16x8*)Bl0 = rb0;
        *(u16x8*)Bl1 = rb1;
        *(u16x8*)Bl2 = rb2;
        if (kk < 15) {
            int o = (kk + 1) * 64;
            ra0 = *(const u16x8*)(Ag + o);
            ra1 = *(const u16x8*)(Ag + o + 8);
            rb0 = *(const u16x8*)(Bg0 + o);
            rb1 = *(const u16x8*)(Bg1 + o);
            rb2 = *(const u16x8*)(Bg2 + o);
        }
        __syncthreads();
        // A fragments: 4 m-subtiles x 2 k-halves
        bf16x8 fa[4][2];
#pragma unroll
        for (int ms = 0; ms < 4; ++ms) {
            const u16* ar = As + (wm * 64 + ms * 16 + lo4) * 64;
            fa[ms][0] = asbf(*(const u16x8*)(ar + ((hi2 * 8) ^ rsw)));
            fa[ms][1] = asbf(*(const u16x8*)(ar + ((hi2 * 8 + 32) ^ rsw)));
        }
        __builtin_amdgcn_s_setprio(1);
#pragma unroll
        for (int fj = 0; fj < 3; ++fj) {
            const u16* br = Bst + (wn * 48 + fj * 16 + lo4) * 64;
            bf16x8 fb0 = asbf(*(const u16x8*)(br + ((hi2 * 8) ^ rsw)));
            bf16x8 fb1 = asbf(*(const u16x8*)(br + ((hi2 * 8 + 32) ^ rsw)));
#pragma unroll
            for (int ms = 0; ms < 4; ++ms) {
                acc[ms][fj] = __builtin_amdgcn_mfma_f32_16x16x32_bf16(fa[ms][0], fb0, acc[ms][fj], 0, 0, 0);
                acc[ms][fj] = __builtin_amdgcn_mfma_f32_16x16x32_bf16(fa[ms][1], fb1, acc[ms][fj], 0, 0, 0);
            }
        }
        __builtin_amdgcn_s_setprio(0);
    }

    // epilogue: LDS bounce per section for vectorized global stores
    const int b = st >> 4, s128 = (st & 15) * 128;
    u16* Cs = As;  // 16KB reuse
#pragma unroll
    for (int sec = 0; sec < 3; ++sec) {
        __syncthreads();
#pragma unroll
        for (int fj = 0; fj < 3; ++fj) {
            const int base = wn * 48 + fj * 16;
            if ((base >> 6) == sec) {
                const int col = base - sec * 64 + lo4;
#pragma unroll
                for (int ms = 0; ms < 4; ++ms)
#pragma unroll
                    for (int r = 0; r < 4; ++r)
                        Cs[(wm * 64 + ms * 16 + hi2 * 4 + r) * 64 + col] = f2b(acc[ms][fj][r]);
            }
        }
        __syncthreads();
        if (sec == 2) {
            // V: transpose to vt[bn][h][s]
            const int h = t & 63, sb = t >> 6;
            u16x8 o0, o1;
#pragma unroll
            for (int e = 0; e < 8; ++e) o0[e] = Cs[(sb * 16 + e) * 64 + h];
#pragma unroll
            for (int e = 0; e < 8; ++e) o1[e] = Cs[(sb * 16 + 8 + e) * 64 + h];
            u16* dst = vt + ((size_t)(b * 16 + n) * 64 + h) * 2048 + s128 + sb * 16;
            *(u16x8*)dst = o0;
            *(u16x8*)(dst + 8) = o1;
        } else {
            const int row = t >> 2, off = (t & 3) * 16;
            u16* dst = (sec == 0) ? qbuf : kbuf;
            dst += ((size_t)(b * 16 + n) * 2048 + s128 + row) * 64 + off;
            *(u16x8*)dst = *(const u16x8*)(Cs + row * 64 + off);
            *(u16x8*)(dst + 8) = *(const u16x8*)(Cs + row * 64 + off + 8);
        }
    }
}

// ---------------------------------------------------------------------------
// MFMA flash attention, swapped-operand form. QBLK=128 (8 waves x 16 q-cols),
// KVBLK=128. exp2-domain softmax (scale folded into W), defer-max (THR=8),
// per-lane-local softmax; P via cvt_pk into wave-private swizzled LDS.
__global__ __launch_bounds__(512) void k_attn(const u16* __restrict__ qbuf,
                                              const u16* __restrict__ kbuf,
                                              const u16* __restrict__ vt,
                                              float* __restrict__ obuf) {
    __shared__ u16 Ks[128 * 64];       // [kv][64h] swizzled, 16KB
    __shared__ u16 Vs[64 * 128];       // [h][128kv] swizzled, 16KB
    __shared__ u16 Ps[8 * 16 * 128];   // per-wave [16q][128kv] swizzled, 32KB
    const int p = blockIdx.x;
    const int j = p >> 3;
    const int bn = (p & 7) * 4 + (j & 3);   // 4 bn per XCD-ish group
    const int qb = 15 - (j >> 2);           // LPT: heavy q-tiles first
    const int t = threadIdx.x;
    const int w = t >> 6, lane = t & 63, hi2 = lane >> 4, lo4 = lane & 15;

    // Q as B-operand fragments (col = q = lo4, k = h = hi2*8+e)
    const int q = qb * 128 + w * 16 + lo4;
    const u16* Qp = qbuf + ((size_t)bn * 2048 + q) * 64;
    bf16x8 bq0 = asbf(*(const u16x8*)(Qp + hi2 * 8));
    bf16x8 bq1 = asbf(*(const u16x8*)(Qp + 32 + hi2 * 8));

    // staging: K 128x64 (row t>>2, 32B), V 64x128 (row t>>3, 32B)
    const int krow = t >> 2, kq4 = t & 3;
    const u16* Kg = kbuf + (size_t)bn * 2048 * 64 + (size_t)krow * 64 + kq4 * 16;
    const int ksw = (krow & 7) << 3;
    u16* Kl0 = Ks + krow * 64 + ((kq4 * 16 + 0) ^ ksw);
    u16* Kl1 = Ks + krow * 64 + ((kq4 * 16 + 8) ^ ksw);
    const int vrow = t >> 3, vo = (t & 7) * 16;
    const u16* Vg = vt + (size_t)bn * 64 * 2048 + (size_t)vrow * 2048 + vo;
    const int vsw = (vrow & 7) << 3;
    u16* Vl0 = Vs + vrow * 128 + ((vo + 0) ^ vsw);
    u16* Vl1 = Vs + vrow * 128 + ((vo + 8) ^ vsw);

    f4v accO[4];
#pragma unroll
    for (int i = 0; i < 4; ++i) accO[i] = (f4v){0.f, 0.f, 0.f, 0.f};
    float m = -3.0e38f, l = 0.f;

    const int rsw = (lo4 & 7) << 3;
    u16* Pw = Ps + w * 2048 + lo4 * 128;  // this lane's q-row
    const int nkb = qb + 1;

    u16x8 kr0 = *(const u16x8*)(Kg);
    u16x8 kr1 = *(const u16x8*)(Kg + 8);
    u16x8 vr0 = *(const u16x8*)(Vg);
    u16x8 vr1 = *(const u16x8*)(Vg + 8);

    for (int kb = 0; kb < nkb; ++kb) {
        __syncthreads();  // previous tile fully consumed
        *(u16x8*)Kl0 = kr0;
        *(u16x8*)Kl1 = kr1;
        *(u16x8*)Vl0 = vr0;
        *(u16x8*)Vl1 = vr1;
        if (kb + 1 < nkb) {
            kr0 = *(const u16x8*)(Kg + (size_t)(kb + 1) * 8192);
            kr1 = *(const u16x8*)(Kg + (size_t)(kb + 1) * 8192 + 8);
            vr0 = *(const u16x8*)(Vg + (kb + 1) * 128);
            vr1 = *(const u16x8*)(Vg + (kb + 1) * 128 + 8);
        }
        __syncthreads();  // staged tile visible

        // S^T = K Q : D[kv][q], kv = fi*16 + hi2*4 + r (fi 0..7)
        f4v s4[8];
#pragma unroll
        for (int i = 0; i < 8; ++i) s4[i] = (f4v){0.f, 0.f, 0.f, 0.f};
        __builtin_amdgcn_s_setprio(1);
#pragma unroll
        for (int fi = 0; fi < 8; ++fi) {
            const u16* kr = Ks + (fi * 16 + lo4) * 64;
            bf16x8 ka0 = asbf(*(const u16x8*)(kr + ((hi2 * 8) ^ rsw)));
            bf16x8 ka1 = asbf(*(const u16x8*)(kr + ((hi2 * 8 + 32) ^ rsw)));
            s4[fi] = __builtin_amdgcn_mfma_f32_16x16x32_bf16(ka0, bq0, s4[fi], 0, 0, 0);
            s4[fi] = __builtin_amdgcn_mfma_f32_16x16x32_bf16(ka1, bq1, s4[fi], 0, 0, 0);
        }
        __builtin_amdgcn_s_setprio(0);

        // causal mask (diagonal tile only)
        if (kb == qb) {
#pragma unroll
            for (int fi = 0; fi < 8; ++fi)
#pragma unroll
                for (int r = 0; r < 4; ++r) {
                    int kvg = kb * 128 + fi * 16 + hi2 * 4 + r;
                    if (kvg > q) s4[fi][r] = -3.0e38f;
                }
        }

        // per-lane softmax over 32 local kv values (+2 shfl across hi2)
        float pm = s4[0][0];
#pragma unroll
        for (int fi = 0; fi < 8; ++fi)
#pragma unroll
            for (int r = 0; r < 4; ++r) pm = fmaxf(pm, s4[fi][r]);
        pm = fmaxf(pm, __shfl_xor(pm, 16));
        pm = fmaxf(pm, __shfl_xor(pm, 32));

        float ts = 0.f;
        if (__any(pm > m + 8.0f)) {          // rescale path
            float mn = fmaxf(m, pm);
            float fs = __builtin_exp2f(m - mn);
            m = mn;
            l *= fs;
#pragma unroll
            for (int fh = 0; fh < 4; ++fh)
#pragma unroll
                for (int r = 0; r < 4; ++r) accO[fh][r] *= fs;
        }
#pragma unroll
        for (int fi = 0; fi < 8; ++fi) {
#pragma unroll
            for (int r = 0; r < 4; ++r) {
                float pv = __builtin_exp2f(s4[fi][r] - m);
                s4[fi][r] = pv;
                ts += pv;
            }
            u32x2 pk;
            pk[0] = cvtpk(s4[fi][0], s4[fi][1]);
            pk[1] = cvtpk(s4[fi][2], s4[fi][3]);
            *(u32x2*)(Pw + ((fi * 16 + hi2 * 4) ^ rsw)) = pk;
        }
        ts += __shfl_xor(ts, 16);
        ts += __shfl_xor(ts, 32);
        l += ts;

        // O^T += V^T P^T : kv is K-dim, 4 k-subtiles of 32
        bf16x8 pb[4];
#pragma unroll
        for (int ks = 0; ks < 4; ++ks)
            pb[ks] = asbf(*(const u16x8*)(Pw + ((ks * 32 + hi2 * 8) ^ rsw)));
        __builtin_amdgcn_s_setprio(1);
#pragma unroll
        for (int fh = 0; fh < 4; ++fh) {
            const u16* vr = Vs + (fh * 16 + lo4) * 128;
#pragma unroll
            for (int ks = 0; ks < 4; ++ks) {
                bf16x8 va = asbf(*(const u16x8*)(vr + ((ks * 32 + hi2 * 8) ^ rsw)));
                accO[fh] = __builtin_amdgcn_mfma_f32_16x16x32_bf16(va, pb[ks], accO[fh], 0, 0, 0);
            }
        }
        __builtin_amdgcn_s_setprio(0);
    }

    // normalize + store fp32 [s][h]
    float inv = 1.f / l;
    float* orow = obuf + ((size_t)bn * 2048 + q) * 64;
#pragma unroll
    for (int fh = 0; fh < 4; ++fh)
#pragma unroll
        for (int r = 0; r < 4; ++r)
            orow[fh * 16 + hi2 * 4 + r] = accO[fh][r] * inv;
}

// ---------------------------------------------------------------------------
// K4: permute + scale. final[b,s2,64n+rr] = attn[b,n, 32rr+s2/64, s2%64] * wsum[64n+rr]
__global__ __launch_bounds__(256) void k_perm(const float* __restrict__ obuf,
                                              const float* __restrict__ wsum,
                                              float* __restrict__ out) {
    __shared__ float T[64][65];
    const int tt = blockIdx.x, n = blockIdx.y, b = blockIdx.z;
    const int tid = threadIdx.x;
    const float* src = obuf + ((size_t)(b * 16 + n) * S_) * H_;
#pragma unroll
    for (int rep = 0; rep < 4; ++rep) {
        int v = tid + rep * 256;
        int r = v >> 4, h4 = v & 15;
        float4 f = *(const float4*)(src + (size_t)(r * 32 + tt) * H_ + h4 * 4);
        T[r][h4 * 4 + 0] = f.x;
        T[r][h4 * 4 + 1] = f.y;
        T[r][h4 * 4 + 2] = f.z;
        T[r][h4 * 4 + 3] = f.w;
    }
    __syncthreads();
#pragma unroll
    for (int rep = 0; rep < 4; ++rep) {
        int v = tid + rep * 256;
        int h = v >> 4, r4 = v & 15;
        float4 w4 = *(const float4*)(wsum + n * 64 + r4 * 4);
        float4 o4 = make_float4(T[r4 * 4 + 0][h] * w4.x, T[r4 * 4 + 1][h] * w4.y,
                                T[r4 * 4 + 2][h] * w4.z, T[r4 * 4 + 3][h] * w4.w);
        *(float4*)(out + ((size_t)(b * S_ + tt * 64 + h) * D_) + n * 64 + r4 * 4) = o4;
    }
}

// ---------------------------------------------------------------------------
extern "C" void kernel_launch(void* const* d_in, const int* in_sizes, int n_in,
                              void* d_out, int out_size, void* d_ws, size_t ws_size,
                              hipStream_t stream) {
    const float* x = (const float*)d_in[0];
    const float* Wqkv = (const float*)d_in[1];
    const float* Wout = (const float*)d_in[2];
    float* out = (float*)d_out;

    char* p = (char*)d_ws;
    float* wsum = (float*)p; p += 4096;
    u16* xb = (u16*)p; p += (size_t)4096 * 1024 * 2;          // 8 MB
    u16* wt = (u16*)p; p += (size_t)16 * 192 * 1024 * 2;      // 6 MB
    u16* qb_ = (u16*)p; p += (size_t)32 * 2048 * 64 * 2;      // 8 MB
    u16* kb_ = (u16*)p; p += (size_t)32 * 2048 * 64 * 2;      // 8 MB
    u16* vt_ = (u16*)p; p += (size_t)32 * 2048 * 64 * 2;      // 8 MB
    float* ob_ = (float*)p;                                   // 16 MB

    k_cvt_x<<<2048, 256, 0, stream>>>(x, xb);
    k_cvt_w<<<dim3(16, 3, 16), 256, 0, stream>>>(Wqkv, wt);
    k_wsum<<<64, 256, 0, stream>>>(Wout, wsum);
    k_qkv<<<dim3(32, 16), 512, 0, stream>>>(xb, wt, qb_, kb_, vt_);
    k_attn<<<512, 512, 0, stream>>>(qb_, kb_, vt_, ob_);
    k_perm<<<dim3(32, 16, 2), 256, 0, stream>>>(ob_, wsum, out);
}

// Round 6
// 105.729 us; speedup vs baseline: 1.0209x; 1.0209x over previous
//
#include <hip/hip_runtime.h>
#include <hip/hip_bf16.h>

#define B_ 2
#define S_ 2048
#define D_ 1024
#define N_ 16
#define H_ 64

typedef unsigned short u16;
typedef unsigned int u32;
typedef __bf16 bf16x8 __attribute__((ext_vector_type(8)));
typedef u16 u16x8 __attribute__((ext_vector_type(8)));
typedef u32 u32x2 __attribute__((ext_vector_type(2)));
typedef float f4v __attribute__((ext_vector_type(4)));

__device__ __forceinline__ u16 f2b(float f) {
    u32 u = __builtin_bit_cast(u32, f);
    u32 r = (u + 0x7FFFu + ((u >> 16) & 1u)) >> 16;
    return (u16)r;
}
__device__ __forceinline__ bf16x8 asbf(u16x8 v) { return __builtin_bit_cast(bf16x8, v); }
__device__ __forceinline__ u32 cvtpk(float a, float b) {
    u32 r;
    asm("v_cvt_pk_bf16_f32 %0, %1, %2" : "=v"(r) : "v"(a), "v"(b));
    return r;
}

// ---------------------------------------------------------------------------
// convert x fp32 -> bf16 [4096][1024]
__global__ __launch_bounds__(256) void k_cvt_x(const float* __restrict__ x,
                                               u16* __restrict__ xb) {
    size_t i = ((size_t)blockIdx.x * 256 + threadIdx.x) * 8;
    float4 f0 = *(const float4*)(x + i);
    float4 f1 = *(const float4*)(x + i + 4);
    u16x8 o;
    o[0] = f2b(f0.x); o[1] = f2b(f0.y); o[2] = f2b(f0.z); o[3] = f2b(f0.w);
    o[4] = f2b(f1.x); o[5] = f2b(f1.y); o[6] = f2b(f1.z); o[7] = f2b(f1.w);
    *(u16x8*)(xb + i) = o;
}

// ---------------------------------------------------------------------------
// W_qkv fp32 [n][1024 d][192 j] -> bf16 TRANSPOSED wt [n][192 j][1024 d].
// Q columns (j<64) scaled by 0.125*log2(e) (exp2-domain softmax).
__global__ __launch_bounds__(256) void k_cvt_w(const float* __restrict__ w,
                                               u16* __restrict__ wt) {
    __shared__ float T[64][65];
    const int d0 = blockIdx.x * 64, jt = blockIdx.y, n = blockIdx.z;
    const int j0 = jt * 64;
    const float sc = (jt == 0) ? 0.125f * 1.44269504089f : 1.0f;
    const int t = threadIdx.x;
#pragma unroll
    for (int rep = 0; rep < 4; ++rep) {
        int v = t + rep * 256;
        int row = v >> 4, c4 = v & 15;
        float4 f = *(const float4*)(w + ((size_t)(n * 1024 + d0 + row)) * 192 + j0 + c4 * 4);
        T[row][c4 * 4 + 0] = f.x * sc;
        T[row][c4 * 4 + 1] = f.y * sc;
        T[row][c4 * 4 + 2] = f.z * sc;
        T[row][c4 * 4 + 3] = f.w * sc;
    }
    __syncthreads();
#pragma unroll
    for (int rep = 0; rep < 2; ++rep) {
        int c = t + rep * 256;
        int j = c >> 3, db = c & 7;
        u16x8 o;
#pragma unroll
        for (int e = 0; e < 8; ++e) o[e] = f2b(T[db * 8 + e][j]);
        *(u16x8*)(wt + ((size_t)(n * 192 + j0 + j)) * 1024 + d0 + db * 8) = o;
    }
}

// ---------------------------------------------------------------------------
// wsum[d] = sum over 1024 rows of W_out
__global__ __launch_bounds__(256) void k_wsum(const float* __restrict__ Wout,
                                              float* __restrict__ wsum) {
    __shared__ float red[16][17];
    const int dd = threadIdx.x & 15, rr = threadIdx.x >> 4;
    const int d = blockIdx.x * 16 + dd;
    float s = 0.f;
    for (int r = rr * 64; r < rr * 64 + 64; ++r) s += Wout[(size_t)r * 1024 + d];
    red[rr][dd] = s;
    __syncthreads();
    if (rr == 0) {
        float t = 0.f;
#pragma unroll
        for (int k = 0; k < 16; ++k) t += red[k][dd];
        wsum[d] = t;
    }
}

// ---------------------------------------------------------------------------
// QKV GEMM, MFMA bf16. Tile 128(M) x 192(N) x 64(K-step). 8 waves as 2M x 4N;
// wave tile 64x48 (4 m-subtiles x 3 fj).
__global__ __launch_bounds__(512) void k_qkv(const u16* __restrict__ xb,
                                             const u16* __restrict__ wt,
                                             u16* __restrict__ qbuf,
                                             u16* __restrict__ kbuf,
                                             u16* __restrict__ vt) {
    __shared__ u16 As[128 * 64];   // [row][64k] swizzled
    __shared__ u16 Bst[192 * 64];  // [j][64k]  swizzled
    const int st = blockIdx.x, n = blockIdx.y;
    const int t = threadIdx.x;
    const int w = t >> 6, lane = t & 63, hi2 = lane >> 4, lo4 = lane & 15;
    const int wm = w >> 2, wn = w & 3;  // 2M x 4N wave grid

    const int arow = t >> 2, aq4 = t & 3;
    const u16* Ag = xb + (size_t)(st * 128 + arow) * 1024 + aq4 * 16;
    const int asw = (arow & 7) << 3;
    u16* Al0 = As + arow * 64 + ((aq4 * 16 + 0) ^ asw);
    u16* Al1 = As + arow * 64 + ((aq4 * 16 + 8) ^ asw);
    const int bj = t >> 3, boff = (t & 7) * 8;
    const u16* Bg0 = wt + (size_t)(n * 192 + bj) * 1024 + boff;
    const u16* Bg1 = Bg0 + (size_t)64 * 1024;
    const u16* Bg2 = Bg0 + (size_t)128 * 1024;
    const int bsw = boff ^ ((bj & 7) << 3);
    u16* Bl0 = Bst + (bj + 0) * 64 + bsw;
    u16* Bl1 = Bst + (bj + 64) * 64 + bsw;
    u16* Bl2 = Bst + (bj + 128) * 64 + bsw;

    f4v acc[4][3];
#pragma unroll
    for (int i = 0; i < 4; ++i)
#pragma unroll
        for (int j = 0; j < 3; ++j) acc[i][j] = (f4v){0.f, 0.f, 0.f, 0.f};

    const int rsw = (lo4 & 7) << 3;
    u16x8 ra0 = *(const u16x8*)(Ag);
    u16x8 ra1 = *(const u16x8*)(Ag + 8);
    u16x8 rb0 = *(const u16x8*)(Bg0);
    u16x8 rb1 = *(const u16x8*)(Bg1);
    u16x8 rb2 = *(const u16x8*)(Bg2);

    for (int kk = 0; kk < 16; ++kk) {
        __syncthreads();
        *(u16x8*)Al0 = ra0;
        *(u16x8*)Al1 = ra1;
        *(u16x8*)Bl0 = rb0;
        *(u16x8*)Bl1 = rb1;
        *(u16x8*)Bl2 = rb2;
        if (kk < 15) {
            int o = (kk + 1) * 64;
            ra0 = *(const u16x8*)(Ag + o);
            ra1 = *(const u16x8*)(Ag + o + 8);
            rb0 = *(const u16x8*)(Bg0 + o);
            rb1 = *(const u16x8*)(Bg1 + o);
            rb2 = *(const u16x8*)(Bg2 + o);
        }
        __syncthreads();
        bf16x8 fa[4][2];
#pragma unroll
        for (int ms = 0; ms < 4; ++ms) {
            const u16* ar = As + (wm * 64 + ms * 16 + lo4) * 64;
            fa[ms][0] = asbf(*(const u16x8*)(ar + ((hi2 * 8) ^ rsw)));
            fa[ms][1] = asbf(*(const u16x8*)(ar + ((hi2 * 8 + 32) ^ rsw)));
        }
        __builtin_amdgcn_s_setprio(1);
#pragma unroll
        for (int fj = 0; fj < 3; ++fj) {
            const u16* br = Bst + (wn * 48 + fj * 16 + lo4) * 64;
            bf16x8 fb0 = asbf(*(const u16x8*)(br + ((hi2 * 8) ^ rsw)));
            bf16x8 fb1 = asbf(*(const u16x8*)(br + ((hi2 * 8 + 32) ^ rsw)));
#pragma unroll
            for (int ms = 0; ms < 4; ++ms) {
                acc[ms][fj] = __builtin_amdgcn_mfma_f32_16x16x32_bf16(fa[ms][0], fb0, acc[ms][fj], 0, 0, 0);
                acc[ms][fj] = __builtin_amdgcn_mfma_f32_16x16x32_bf16(fa[ms][1], fb1, acc[ms][fj], 0, 0, 0);
            }
        }
        __builtin_amdgcn_s_setprio(0);
    }

    const int b = st >> 4, s128 = (st & 15) * 128;
    u16* Cs = As;
#pragma unroll
    for (int sec = 0; sec < 3; ++sec) {
        __syncthreads();
#pragma unroll
        for (int fj = 0; fj < 3; ++fj) {
            const int base = wn * 48 + fj * 16;
            if ((base >> 6) == sec) {
                const int col = base - sec * 64 + lo4;
#pragma unroll
                for (int ms = 0; ms < 4; ++ms)
#pragma unroll
                    for (int r = 0; r < 4; ++r)
                        Cs[(wm * 64 + ms * 16 + hi2 * 4 + r) * 64 + col] = f2b(acc[ms][fj][r]);
            }
        }
        __syncthreads();
        if (sec == 2) {
            const int h = t & 63, sb = t >> 6;
            u16x8 o0, o1;
#pragma unroll
            for (int e = 0; e < 8; ++e) o0[e] = Cs[(sb * 16 + e) * 64 + h];
#pragma unroll
            for (int e = 0; e < 8; ++e) o1[e] = Cs[(sb * 16 + 8 + e) * 64 + h];
            u16* dst = vt + ((size_t)(b * 16 + n) * 64 + h) * 2048 + s128 + sb * 16;
            *(u16x8*)dst = o0;
            *(u16x8*)(dst + 8) = o1;
        } else {
            const int row = t >> 2, off = (t & 3) * 16;
            u16* dst = (sec == 0) ? qbuf : kbuf;
            dst += ((size_t)(b * 16 + n) * 2048 + s128 + row) * 64 + off;
            *(u16x8*)dst = *(const u16x8*)(Cs + row * 64 + off);
            *(u16x8*)(dst + 8) = *(const u16x8*)(Cs + row * 64 + off + 8);
        }
    }
}

// ---------------------------------------------------------------------------
// MFMA flash attention, swapped-operand. QBLK=64 (4 waves x 16 q-cols),
// KVBLK=64, grid 1024 (finer LPT, 6 blocks/CU by 24KB LDS). exp2-domain
// softmax, defer-max (THR=8), T14 prefetch. Swizzled LDS-bounce epilogue.
__global__ __launch_bounds__(256) void k_attn(const u16* __restrict__ qbuf,
                                              const u16* __restrict__ kbuf,
                                              const u16* __restrict__ vt,
                                              float* __restrict__ obuf) {
    __shared__ u16 SMEM[64 * 64 + 64 * 64 + 4 * 16 * 64];  // Ks | Vs | Ps = 24KB
    u16* Ks = SMEM;
    u16* Vs = SMEM + 4096;
    u16* Ps = SMEM + 8192;
    const int id = blockIdx.x;
    const int bn = id & 31;
    const int qb = 31 - (id >> 5);      // LPT: heavy q-tiles dispatched first
    const int t = threadIdx.x;
    const int w = t >> 6, lane = t & 63, hi2 = lane >> 4, lo4 = lane & 15;

    // Q as B-operand fragments (col = q = lo4, k = h = hi2*8+e)
    const int q = qb * 64 + w * 16 + lo4;
    const u16* Qp = qbuf + ((size_t)bn * 2048 + q) * 64;
    bf16x8 bq0 = asbf(*(const u16x8*)(Qp + hi2 * 8));
    bf16x8 bq1 = asbf(*(const u16x8*)(Qp + 32 + hi2 * 8));

    // staging: 256 thr, each 32B of K (row kv) and V (row h)
    const int srow = t >> 2, sq4 = t & 3;
    const u16* Kg = kbuf + (size_t)bn * 2048 * 64 + (size_t)srow * 64 + sq4 * 16;
    const u16* Vg = vt + (size_t)bn * 64 * 2048 + (size_t)srow * 2048 + sq4 * 16;
    const int ssw = (srow & 7) << 3;
    u16* Kl0 = Ks + srow * 64 + ((sq4 * 16 + 0) ^ ssw);
    u16* Kl1 = Ks + srow * 64 + ((sq4 * 16 + 8) ^ ssw);
    u16* Vl0 = Vs + srow * 64 + ((sq4 * 16 + 0) ^ ssw);
    u16* Vl1 = Vs + srow * 64 + ((sq4 * 16 + 8) ^ ssw);

    f4v accO[4];
#pragma unroll
    for (int i = 0; i < 4; ++i) accO[i] = (f4v){0.f, 0.f, 0.f, 0.f};
    float m = -3.0e38f, l = 0.f;

    const int rsw = (lo4 & 7) << 3;
    u16* Pw = Ps + w * 1024 + lo4 * 64;  // this lane's q-row
    const int nkb = qb + 1;

    u16x8 kr0 = *(const u16x8*)(Kg);
    u16x8 kr1 = *(const u16x8*)(Kg + 8);
    u16x8 vr0 = *(const u16x8*)(Vg);
    u16x8 vr1 = *(const u16x8*)(Vg + 8);

    for (int kb = 0; kb < nkb; ++kb) {
        __syncthreads();  // previous tile fully consumed
        *(u16x8*)Kl0 = kr0;
        *(u16x8*)Kl1 = kr1;
        *(u16x8*)Vl0 = vr0;
        *(u16x8*)Vl1 = vr1;
        if (kb + 1 < nkb) {
            kr0 = *(const u16x8*)(Kg + (size_t)(kb + 1) * 4096);
            kr1 = *(const u16x8*)(Kg + (size_t)(kb + 1) * 4096 + 8);
            vr0 = *(const u16x8*)(Vg + (kb + 1) * 64);
            vr1 = *(const u16x8*)(Vg + (kb + 1) * 64 + 8);
        }
        __syncthreads();  // staged tile visible

        // S^T = K Q : D[kv][q], kv = fi*16 + hi2*4 + r
        f4v s4[4];
#pragma unroll
        for (int i = 0; i < 4; ++i) s4[i] = (f4v){0.f, 0.f, 0.f, 0.f};
        __builtin_amdgcn_s_setprio(1);
#pragma unroll
        for (int fi = 0; fi < 4; ++fi) {
            const u16* kr = Ks + (fi * 16 + lo4) * 64;
            bf16x8 ka0 = asbf(*(const u16x8*)(kr + ((hi2 * 8) ^ rsw)));
            bf16x8 ka1 = asbf(*(const u16x8*)(kr + ((hi2 * 8 + 32) ^ rsw)));
            s4[fi] = __builtin_amdgcn_mfma_f32_16x16x32_bf16(ka0, bq0, s4[fi], 0, 0, 0);
            s4[fi] = __builtin_amdgcn_mfma_f32_16x16x32_bf16(ka1, bq1, s4[fi], 0, 0, 0);
        }
        __builtin_amdgcn_s_setprio(0);

        // causal mask (diagonal tile only)
        if (kb == qb) {
#pragma unroll
            for (int fi = 0; fi < 4; ++fi)
#pragma unroll
                for (int r = 0; r < 4; ++r) {
                    int kvg = kb * 64 + fi * 16 + hi2 * 4 + r;
                    if (kvg > q) s4[fi][r] = -3.0e38f;
                }
        }

        // per-lane softmax over 16 local kv values (+2 shfl across hi2)
        float pm = s4[0][0];
#pragma unroll
        for (int fi = 0; fi < 4; ++fi)
#pragma unroll
            for (int r = 0; r < 4; ++r) pm = fmaxf(pm, s4[fi][r]);
        pm = fmaxf(pm, __shfl_xor(pm, 16));
        pm = fmaxf(pm, __shfl_xor(pm, 32));

        if (__any(pm > m + 8.0f)) {  // rescale path (defer-max)
            float mn = fmaxf(m, pm);
            float fs = __builtin_exp2f(m - mn);
            m = mn;
            l *= fs;
#pragma unroll
            for (int fh = 0; fh < 4; ++fh)
#pragma unroll
                for (int r = 0; r < 4; ++r) accO[fh][r] *= fs;
        }
        float ts = 0.f;
#pragma unroll
        for (int fi = 0; fi < 4; ++fi) {
#pragma unroll
            for (int r = 0; r < 4; ++r) {
                float pv = __builtin_exp2f(s4[fi][r] - m);
                s4[fi][r] = pv;
                ts += pv;
            }
            u32x2 pk;
            pk[0] = cvtpk(s4[fi][0], s4[fi][1]);
            pk[1] = cvtpk(s4[fi][2], s4[fi][3]);
            *(u32x2*)(Pw + ((fi * 16 + hi2 * 4) ^ rsw)) = pk;
        }
        ts += __shfl_xor(ts, 16);
        ts += __shfl_xor(ts, 32);
        l += ts;

        // O^T += V^T P^T
        bf16x8 pb0 = asbf(*(const u16x8*)(Pw + ((hi2 * 8) ^ rsw)));
        bf16x8 pb1 = asbf(*(const u16x8*)(Pw + ((32 + hi2 * 8) ^ rsw)));
        __builtin_amdgcn_s_setprio(1);
#pragma unroll
        for (int fh = 0; fh < 4; ++fh) {
            const u16* vr = Vs + (fh * 16 + lo4) * 64;
            bf16x8 va0 = asbf(*(const u16x8*)(vr + ((hi2 * 8) ^ rsw)));
            bf16x8 va1 = asbf(*(const u16x8*)(vr + ((hi2 * 8 + 32) ^ rsw)));
            accO[fh] = __builtin_amdgcn_mfma_f32_16x16x32_bf16(va0, pb0, accO[fh], 0, 0, 0);
            accO[fh] = __builtin_amdgcn_mfma_f32_16x16x32_bf16(va1, pb1, accO[fh], 0, 0, 0);
        }
        __builtin_amdgcn_s_setprio(0);
    }

    // epilogue: swizzled LDS bounce (reuse Ks+Vs as f32[64][64]) -> coalesced
    __syncthreads();
    float* Osh = (float*)SMEM;
    {
        float inv = 1.f / l;
        const int orow = w * 16 + lo4;
        const int osw = (lo4 & 7) << 2;  // 4-f32 granule xor
        float* Or = Osh + orow * 64;
#pragma unroll
        for (int fh = 0; fh < 4; ++fh) {
            f4v o;
#pragma unroll
            for (int r = 0; r < 4; ++r) o[r] = accO[fh][r] * inv;
            *(f4v*)(Or + ((fh * 16 + hi2 * 4) ^ osw)) = o;
        }
    }
    __syncthreads();
    {
        const int r2 = t >> 2, c16 = (t & 3) * 16;
        const int rsw2 = (r2 & 7) << 2;
        float* dst = obuf + ((size_t)bn * 2048 + qb * 64 + r2) * 64 + c16;
        const float* srcr = Osh + r2 * 64;
#pragma unroll
        for (int e = 0; e < 4; ++e)
            *(float4*)(dst + e * 4) = *(const float4*)(srcr + ((c16 + e * 4) ^ rsw2));
    }
}

// ---------------------------------------------------------------------------
// K4: permute + scale. final[b,s2,64n+rr] = attn[b,n, 32rr+s2/64, s2%64] * wsum[64n+rr]
__global__ __launch_bounds__(256) void k_perm(const float* __restrict__ obuf,
                                              const float* __restrict__ wsum,
                                              float* __restrict__ out) {
    __shared__ float T[64][65];
    const int tt = blockIdx.x, n = blockIdx.y, b = blockIdx.z;
    const int tid = threadIdx.x;
    const float* src = obuf + ((size_t)(b * 16 + n) * S_) * H_;
#pragma unroll
    for (int rep = 0; rep < 4; ++rep) {
        int v = tid + rep * 256;
        int r = v >> 4, h4 = v & 15;
        float4 f = *(const float4*)(src + (size_t)(r * 32 + tt) * H_ + h4 * 4);
        T[r][h4 * 4 + 0] = f.x;
        T[r][h4 * 4 + 1] = f.y;
        T[r][h4 * 4 + 2] = f.z;
        T[r][h4 * 4 + 3] = f.w;
    }
    __syncthreads();
#pragma unroll
    for (int rep = 0; rep < 4; ++rep) {
        int v = tid + rep * 256;
        int h = v >> 4, r4 = v & 15;
        float4 w4 = *(const float4*)(wsum + n * 64 + r4 * 4);
        float4 o4 = make_float4(T[r4 * 4 + 0][h] * w4.x, T[r4 * 4 + 1][h] * w4.y,
                                T[r4 * 4 + 2][h] * w4.z, T[r4 * 4 + 3][h] * w4.w);
        *(float4*)(out + ((size_t)(b * S_ + tt * 64 + h) * D_) + n * 64 + r4 * 4) = o4;
    }
}

// ---------------------------------------------------------------------------
extern "C" void kernel_launch(void* const* d_in, const int* in_sizes, int n_in,
                              void* d_out, int out_size, void* d_ws, size_t ws_size,
                              hipStream_t stream) {
    const float* x = (const float*)d_in[0];
    const float* Wqkv = (const float*)d_in[1];
    const float* Wout = (const float*)d_in[2];
    float* out = (float*)d_out;

    char* p = (char*)d_ws;
    float* wsum = (float*)p; p += 4096;
    u16* xb = (u16*)p; p += (size_t)4096 * 1024 * 2;          // 8 MB
    u16* wt = (u16*)p; p += (size_t)16 * 192 * 1024 * 2;      // 6 MB
    u16* qb_ = (u16*)p; p += (size_t)32 * 2048 * 64 * 2;      // 8 MB
    u16* kb_ = (u16*)p; p += (size_t)32 * 2048 * 64 * 2;      // 8 MB
    u16* vt_ = (u16*)p; p += (size_t)32 * 2048 * 64 * 2;      // 8 MB
    float* ob_ = (float*)p;                                   // 16 MB

    k_cvt_x<<<2048, 256, 0, stream>>>(x, xb);
    k_cvt_w<<<dim3(16, 3, 16), 256, 0, stream>>>(Wqkv, wt);
    k_wsum<<<64, 256, 0, stream>>>(Wout, wsum);
    k_qkv<<<dim3(32, 16), 512, 0, stream>>>(xb, wt, qb_, kb_, vt_);
    k_attn<<<1024, 256, 0, stream>>>(qb_, kb_, vt_, ob_);
    k_perm<<<dim3(32, 16, 2), 256, 0, stream>>>(ob_, wsum, out);
}